// Round 1
// baseline (440.101 us; speedup 1.0000x reference)
//
#include <hip/hip_runtime.h>
#include <hip/hip_bf16.h>

#define N_NODES 50000
#define N_EDGES 800000
#define N_GRAPHS 512
#define EMB 64
#define HID 128

// ---------------------------------------------------------------- embed gather
__global__ void k_embed(const int* __restrict__ x, const float* __restrict__ emb,
                        float* __restrict__ h0) {
    int t = blockIdx.x * 256 + threadIdx.x;          // N*16 threads, float4 each
    if (t >= N_NODES * 16) return;
    int n = t >> 4, c4 = t & 15;
    const float4* e4 = (const float4*)emb;
    float4 v = e4[(size_t)x[n] * 16 + c4];
    ((float4*)h0)[(size_t)n * 16 + c4] = v;
}

// ---------------------------------------------------------------- degree hist
__global__ void k_hist(const int* __restrict__ ei, int* __restrict__ deg) {
    int e = blockIdx.x * 256 + threadIdx.x;
    if (e >= N_EDGES) return;
    atomicAdd(&deg[ei[N_EDGES + e]], 1);             // dst row
}

// ---------------------------------------------------------------- 3-phase scan
__global__ void k_scanA(const int* __restrict__ deg, int* __restrict__ rowptr,
                        int* __restrict__ bsums) {
    __shared__ int s[256];
    int t = threadIdx.x, i = blockIdx.x * 256 + t;
    int v = (i < N_NODES) ? deg[i] : 0;
    s[t] = v; __syncthreads();
    int xv = v;
    for (int off = 1; off < 256; off <<= 1) {
        int y = (t >= off) ? s[t - off] : 0;
        __syncthreads();
        xv += y; s[t] = xv;
        __syncthreads();
    }
    if (i < N_NODES) rowptr[i] = xv - v;             // block-local exclusive
    if (t == 255) bsums[blockIdx.x] = xv;
}

__global__ void k_scanB(int* __restrict__ bsums, int nb) {
    __shared__ int s[256];
    int t = threadIdx.x;
    int v = (t < nb) ? bsums[t] : 0;
    s[t] = v; __syncthreads();
    int xv = v;
    for (int off = 1; off < 256; off <<= 1) {
        int y = (t >= off) ? s[t - off] : 0;
        __syncthreads();
        xv += y; s[t] = xv;
        __syncthreads();
    }
    if (t < nb) bsums[t] = xv - v;                   // exclusive
}

__global__ void k_scanC(int* __restrict__ rowptr, int* __restrict__ wp,
                        const int* __restrict__ bsums) {
    int i = blockIdx.x * 256 + threadIdx.x;
    if (i < N_NODES) {
        int v = rowptr[i] + bsums[blockIdx.x];
        rowptr[i] = v;
        wp[i] = v;
    }
    if (i == 0) rowptr[N_NODES] = N_EDGES;
}

// ---------------------------------------------------------------- edge scatter
__global__ void k_scatter(const int* __restrict__ ei, int* __restrict__ wp,
                          int* __restrict__ nbr) {
    int e = blockIdx.x * 256 + threadIdx.x;
    if (e >= N_EDGES) return;
    int s = ei[e], d = ei[N_EDGES + e];
    int pos = atomicAdd(&wp[d], 1);
    nbr[pos] = s;
}

// ---------------------------------------------------------------- aggregation
// one wave per node; lane owns feature columns
template <int F>
__global__ void k_agg(const float* __restrict__ h, const int* __restrict__ rowptr,
                      const int* __restrict__ nbr, float* __restrict__ mean) {
    int wid = (blockIdx.x * 256 + threadIdx.x) >> 6;
    int lane = threadIdx.x & 63;
    if (wid >= N_NODES) return;
    int r0 = rowptr[wid], r1 = rowptr[wid + 1];
    float inv = 1.0f / (float)max(r1 - r0, 1);
    if constexpr (F == 64) {
        float acc = 0.0f;
        int i = r0;
        for (; i + 1 < r1; i += 2) {
            int s0 = nbr[i], s1 = nbr[i + 1];
            float a = h[(size_t)s0 * 64 + lane];
            float b = h[(size_t)s1 * 64 + lane];
            acc += a + b;
        }
        if (i < r1) acc += h[(size_t)nbr[i] * 64 + lane];
        mean[(size_t)wid * 64 + lane] = acc * inv;
    } else {
        const float2* h2 = (const float2*)h;
        float ax = 0.0f, ay = 0.0f;
        int i = r0;
        for (; i + 1 < r1; i += 2) {
            int s0 = nbr[i], s1 = nbr[i + 1];
            float2 a = h2[(size_t)s0 * 64 + lane];
            float2 b = h2[(size_t)s1 * 64 + lane];
            ax += a.x + b.x; ay += a.y + b.y;
        }
        if (i < r1) {
            float2 a = h2[(size_t)nbr[i] * 64 + lane];
            ax += a.x; ay += a.y;
        }
        float2* m2 = (float2*)mean;
        m2[(size_t)wid * 64 + lane] = make_float2(ax * inv, ay * inv);
    }
}

// ---------------------------------------------------------------- GEMM tile
// block = 256 thr = 4 waves; block covers 64 nodes; wave w -> out cols [32w,32w+32)
// lane -> node. Weights load as scalar (uniform) s_loads; h rows staged in LDS.
template <int K, bool ADD, bool RELU>
__global__ __launch_bounds__(256) void k_gemm(
    const float* __restrict__ hin, const float* __restrict__ w,
    const float* __restrict__ bias, float* __restrict__ out) {
    constexpr int LS = K + 2;                        // 2-way bank alias = free
    __shared__ float ls[64 * LS];
    int base = blockIdx.x * 64;
    int t = threadIdx.x;

    const float4* h4 = (const float4*)hin;
    for (int idx = t; idx < 64 * (K / 4); idx += 256) {
        int r = idx / (K / 4), c4 = idx % (K / 4);
        float4 v = (base + r < N_NODES) ? h4[(size_t)(base + r) * (K / 4) + c4]
                                        : make_float4(0.f, 0.f, 0.f, 0.f);
        float* d = &ls[r * LS + c4 * 4];
        d[0] = v.x; d[1] = v.y; d[2] = v.z; d[3] = v.w;
    }
    __syncthreads();

    int lane = t & 63;
    int wid = __builtin_amdgcn_readfirstlane(t >> 6);
    int j0 = wid * 32;
    int node = base + lane;
    bool valid = node < N_NODES;

    float acc[32];
    if constexpr (ADD) {
        const float4* o4 = (const float4*)out;
        #pragma unroll
        for (int jj = 0; jj < 8; jj++) {
            float4 v = valid ? o4[(size_t)node * 32 + (j0 >> 2) + jj]
                             : make_float4(0.f, 0.f, 0.f, 0.f);
            acc[jj * 4 + 0] = v.x; acc[jj * 4 + 1] = v.y;
            acc[jj * 4 + 2] = v.z; acc[jj * 4 + 3] = v.w;
        }
    } else {
        #pragma unroll
        for (int j = 0; j < 32; j++) acc[j] = bias[j0 + j];
    }

    const float* lrow = &ls[lane * LS];
    #pragma unroll 4
    for (int k = 0; k < K; k++) {
        float hv = lrow[k];
        const float* wk = &w[(size_t)k * 128 + j0];  // uniform -> s_load
        #pragma unroll
        for (int j = 0; j < 32; j++) acc[j] = fmaf(hv, wk[j], acc[j]);
    }

    if (!valid) return;
    if constexpr (RELU) {
        #pragma unroll
        for (int j = 0; j < 32; j++) acc[j] = fmaxf(acc[j], 0.0f);
    }
    float4* o4 = (float4*)out;
    #pragma unroll
    for (int jj = 0; jj < 8; jj++)
        o4[(size_t)node * 32 + (j0 >> 2) + jj] =
            make_float4(acc[jj * 4 + 0], acc[jj * 4 + 1], acc[jj * 4 + 2], acc[jj * 4 + 3]);
}

// ---------------------------------------------------------------- mean pool
// batch is sorted; one block per graph; binary-search the segment
__global__ void k_pool(const float* __restrict__ h2, const int* __restrict__ batch,
                       float* __restrict__ pooled) {
    int g = blockIdx.x;
    int lo = 0, hi = N_NODES;
    while (lo < hi) { int mid = (lo + hi) >> 1; if (batch[mid] < g) lo = mid + 1; else hi = mid; }
    int s = lo;
    lo = s; hi = N_NODES;
    while (lo < hi) { int mid = (lo + hi) >> 1; if (batch[mid] < g + 1) lo = mid + 1; else hi = mid; }
    int e = lo;

    int f = threadIdx.x & 127, half = threadIdx.x >> 7;
    float acc = 0.0f;
    for (int r = s + half; r < e; r += 2) acc += h2[(size_t)r * 128 + f];
    __shared__ float tmp[256];
    tmp[threadIdx.x] = acc;
    __syncthreads();
    if (half == 0)
        pooled[(size_t)g * 128 + f] = (tmp[f] + tmp[f + 128]) / (float)max(e - s, 1);
}

// ---------------------------------------------------------------- head
__global__ void k_head(const float* __restrict__ pooled, const float* __restrict__ w_out,
                       const float* __restrict__ b_out, float* __restrict__ out) {
    int i = blockIdx.x * 256 + threadIdx.x;
    if (i >= N_GRAPHS * 2) return;
    int g = i >> 1, c = i & 1;
    float acc = 0.0f;
    for (int k = 0; k < 128; k++) acc += pooled[(size_t)g * 128 + k] * w_out[k * 2 + c];
    out[i] = acc + b_out[c];
}

// ---------------------------------------------------------------- launch
extern "C" void kernel_launch(void* const* d_in, const int* in_sizes, int n_in,
                              void* d_out, int out_size, void* d_ws, size_t ws_size,
                              hipStream_t stream) {
    const int*   x      = (const int*)d_in[0];
    const int*   ei     = (const int*)d_in[1];
    const int*   batch  = (const int*)d_in[2];
    const float* emb    = (const float*)d_in[3];
    const float* w1_l   = (const float*)d_in[4];
    const float* b1     = (const float*)d_in[5];
    const float* w1_r   = (const float*)d_in[6];
    const float* w2_l   = (const float*)d_in[7];
    const float* b2     = (const float*)d_in[8];
    const float* w2_r   = (const float*)d_in[9];
    const float* w_out  = (const float*)d_in[10];
    const float* b_out  = (const float*)d_in[11];
    float* out = (float*)d_out;

    // workspace layout (floats)
    float* F = (float*)d_ws;
    float* h0    = F;                                 // N*64
    float* mean1 = h0 + (size_t)N_NODES * 64;         // N*64
    float* h1    = mean1 + (size_t)N_NODES * 64;      // N*128
    float* mean2 = h1 + (size_t)N_NODES * 128;        // N*128
    float* tmp2  = h0;                                // alias: N*128 (h0+mean1 dead by then)
    int*   deg   = (int*)(mean2 + (size_t)N_NODES * 128);
    int*   rowptr= deg + N_NODES;                     // N+1
    int*   wp    = rowptr + N_NODES + 1;              // N
    int*   nbr   = wp + N_NODES;                      // E
    int*   bsums = nbr + N_EDGES;                     // 256
    float* pooled= (float*)(bsums + 256);             // G*128

    const int NB = (N_NODES + 255) / 256;             // 196

    hipMemsetAsync(deg, 0, (size_t)N_NODES * sizeof(int), stream);

    k_embed<<<(N_NODES * 16 + 255) / 256, 256, 0, stream>>>(x, emb, h0);
    k_hist<<<(N_EDGES + 255) / 256, 256, 0, stream>>>(ei, deg);
    k_scanA<<<NB, 256, 0, stream>>>(deg, rowptr, bsums);
    k_scanB<<<1, 256, 0, stream>>>(bsums, NB);
    k_scanC<<<NB, 256, 0, stream>>>(rowptr, wp, bsums);
    k_scatter<<<(N_EDGES + 255) / 256, 256, 0, stream>>>(ei, wp, nbr);

    // layer 1
    k_agg<64><<<(N_NODES + 3) / 4, 256, 0, stream>>>(h0, rowptr, nbr, mean1);
    k_gemm<64, false, false><<<(N_NODES + 63) / 64, 256, 0, stream>>>(h0, w1_r, b1, h1);
    k_gemm<64, true, true><<<(N_NODES + 63) / 64, 256, 0, stream>>>(mean1, w1_l, b1, h1);

    // layer 2
    k_agg<128><<<(N_NODES + 3) / 4, 256, 0, stream>>>(h1, rowptr, nbr, mean2);
    k_gemm<128, false, false><<<(N_NODES + 63) / 64, 256, 0, stream>>>(h1, w2_r, b2, tmp2);
    k_gemm<128, true, true><<<(N_NODES + 63) / 64, 256, 0, stream>>>(mean2, w2_l, b2, tmp2);

    // pool + head
    k_pool<<<N_GRAPHS, 256, 0, stream>>>(tmp2, batch, pooled);
    k_head<<<(N_GRAPHS * 2 + 255) / 256, 256, 0, stream>>>(pooled, w_out, b_out, out);

    (void)in_sizes; (void)n_in; (void)out_size; (void)ws_size;
}

// Round 3
// 387.666 us; speedup vs baseline: 1.1353x; 1.1353x over previous
//
#include <hip/hip_runtime.h>
#include <hip/hip_bf16.h>

#define N_NODES 50000
#define N_EDGES 800000
#define N_GRAPHS 512
#define EMB 64
#define HID 128

// -------------------------------------------- embed gather + degree histogram
// N_NODES*16 == N_EDGES == 800000: one grid does both.
__global__ void k_embed_hist(const int* __restrict__ x, const float* __restrict__ emb,
                             const int* __restrict__ ei, float* __restrict__ h0,
                             int* __restrict__ deg) {
    int t = blockIdx.x * 256 + threadIdx.x;
    if (t >= N_EDGES) return;
    // embed: thread t -> node t>>4, float4 chunk t&15
    int n = t >> 4, c4 = t & 15;
    const float4* e4 = (const float4*)emb;
    ((float4*)h0)[(size_t)n * 16 + c4] = e4[(size_t)x[n] * 16 + c4];
    // hist: thread t -> edge t
    atomicAdd(&deg[ei[N_EDGES + t]], 1);
}

// ---------------------------------------------------------------- 3-phase scan
__global__ void k_scanA(const int* __restrict__ deg, int* __restrict__ rowptr,
                        int* __restrict__ bsums) {
    __shared__ int s[256];
    int t = threadIdx.x, i = blockIdx.x * 256 + t;
    int v = (i < N_NODES) ? deg[i] : 0;
    s[t] = v; __syncthreads();
    int xv = v;
    for (int off = 1; off < 256; off <<= 1) {
        int y = (t >= off) ? s[t - off] : 0;
        __syncthreads();
        xv += y; s[t] = xv;
        __syncthreads();
    }
    if (i < N_NODES) rowptr[i] = xv - v;
    if (t == 255) bsums[blockIdx.x] = xv;
}

__global__ void k_scanB(int* __restrict__ bsums, int nb) {
    __shared__ int s[256];
    int t = threadIdx.x;
    int v = (t < nb) ? bsums[t] : 0;
    s[t] = v; __syncthreads();
    int xv = v;
    for (int off = 1; off < 256; off <<= 1) {
        int y = (t >= off) ? s[t - off] : 0;
        __syncthreads();
        xv += y; s[t] = xv;
        __syncthreads();
    }
    if (t < nb) bsums[t] = xv - v;
}

__global__ void k_scanC(int* __restrict__ rowptr, int* __restrict__ wp,
                        const int* __restrict__ bsums) {
    int i = blockIdx.x * 256 + threadIdx.x;
    if (i < N_NODES) {
        int v = rowptr[i] + bsums[blockIdx.x];
        rowptr[i] = v;
        wp[i] = v;
    }
    if (i == 0) rowptr[N_NODES] = N_EDGES;
}

// ---------------------------------------------------------------- edge scatter
__global__ void k_scatter(const int* __restrict__ ei, int* __restrict__ wp,
                          int* __restrict__ nbr) {
    int e = blockIdx.x * 256 + threadIdx.x;
    if (e >= N_EDGES) return;
    int s = ei[e], d = ei[N_EDGES + e];
    int pos = atomicAdd(&wp[d], 1);
    nbr[pos] = s;
}

// ---------------------------------------------------------------- aggregation
// one wave per node; lane owns feature columns; unroll-4 for MLP
template <int F>
__global__ __launch_bounds__(256) void k_agg(const float* __restrict__ h,
                                             const int* __restrict__ rowptr,
                                             const int* __restrict__ nbr,
                                             float* __restrict__ mean) {
    int wid = (blockIdx.x * 256 + threadIdx.x) >> 6;
    int lane = threadIdx.x & 63;
    if (wid >= N_NODES) return;
    int r0 = rowptr[wid], r1 = rowptr[wid + 1];
    float inv = 1.0f / (float)max(r1 - r0, 1);
    if constexpr (F == 64) {
        float a0 = 0.f, a1 = 0.f, a2 = 0.f, a3 = 0.f;
        int i = r0;
        for (; i + 3 < r1; i += 4) {
            int s0 = nbr[i], s1 = nbr[i + 1], s2 = nbr[i + 2], s3 = nbr[i + 3];
            a0 += h[(size_t)s0 * 64 + lane];
            a1 += h[(size_t)s1 * 64 + lane];
            a2 += h[(size_t)s2 * 64 + lane];
            a3 += h[(size_t)s3 * 64 + lane];
        }
        for (; i < r1; ++i) a0 += h[(size_t)nbr[i] * 64 + lane];
        mean[(size_t)wid * 64 + lane] = ((a0 + a1) + (a2 + a3)) * inv;
    } else {
        const float2* h2 = (const float2*)h;
        float2 a0 = {0.f, 0.f}, a1 = {0.f, 0.f}, a2 = {0.f, 0.f}, a3 = {0.f, 0.f};
        int i = r0;
        for (; i + 3 < r1; i += 4) {
            int s0 = nbr[i], s1 = nbr[i + 1], s2 = nbr[i + 2], s3 = nbr[i + 3];
            float2 v0 = h2[(size_t)s0 * 64 + lane];
            float2 v1 = h2[(size_t)s1 * 64 + lane];
            float2 v2 = h2[(size_t)s2 * 64 + lane];
            float2 v3 = h2[(size_t)s3 * 64 + lane];
            a0.x += v0.x; a0.y += v0.y;
            a1.x += v1.x; a1.y += v1.y;
            a2.x += v2.x; a2.y += v2.y;
            a3.x += v3.x; a3.y += v3.y;
        }
        for (; i < r1; ++i) {
            float2 v = h2[(size_t)nbr[i] * 64 + lane];
            a0.x += v.x; a0.y += v.y;
        }
        float2* m2 = (float2*)mean;
        m2[(size_t)wid * 64 + lane] =
            make_float2(((a0.x + a1.x) + (a2.x + a3.x)) * inv,
                        ((a0.y + a1.y) + (a2.y + a3.y)) * inv);
    }
}

// ---------------------------------------------------------------- fused layer
// out = relu(bias + hself@w_r + hmean@w_l); acc lives in registers across both
// matmuls, LDS tile re-staged between passes. block = 64 nodes x 4 waves,
// wave w -> out cols [32w, 32w+32), lane -> node. Weights via uniform s_loads.
template <int K>
__global__ __launch_bounds__(256) void k_layer(
    const float* __restrict__ hself, const float* __restrict__ hmean,
    const float* __restrict__ w_r, const float* __restrict__ w_l,
    const float* __restrict__ bias, float* __restrict__ out) {
    constexpr int LS = K + 2;
    __shared__ float ls[64 * LS];
    int base = blockIdx.x * 64;
    int t = threadIdx.x;
    int lane = t & 63;
    int wid = __builtin_amdgcn_readfirstlane(t >> 6);
    int j0 = wid * 32;
    int node = base + lane;
    bool valid = node < N_NODES;

    float acc[32];
    #pragma unroll
    for (int j = 0; j < 32; j++) acc[j] = bias[j0 + j];

    const float* lrow = &ls[lane * LS];
    const float4* h4;

    // ---- pass 1: hself @ w_r
    h4 = (const float4*)hself;
    for (int idx = t; idx < 64 * (K / 4); idx += 256) {
        int r = idx / (K / 4), c4 = idx % (K / 4);
        float4 v = (base + r < N_NODES) ? h4[(size_t)(base + r) * (K / 4) + c4]
                                        : make_float4(0.f, 0.f, 0.f, 0.f);
        float* dp = &ls[r * LS + c4 * 4];
        dp[0] = v.x; dp[1] = v.y; dp[2] = v.z; dp[3] = v.w;
    }
    __syncthreads();
    #pragma unroll 4
    for (int k = 0; k < K; k++) {
        float hv = lrow[k];
        const float* wk = &w_r[(size_t)k * 128 + j0];
        #pragma unroll
        for (int j = 0; j < 32; j++) acc[j] = fmaf(hv, wk[j], acc[j]);
    }
    __syncthreads();   // everyone done reading pass-1 tile

    // ---- pass 2: hmean @ w_l
    h4 = (const float4*)hmean;
    for (int idx = t; idx < 64 * (K / 4); idx += 256) {
        int r = idx / (K / 4), c4 = idx % (K / 4);
        float4 v = (base + r < N_NODES) ? h4[(size_t)(base + r) * (K / 4) + c4]
                                        : make_float4(0.f, 0.f, 0.f, 0.f);
        float* dp = &ls[r * LS + c4 * 4];
        dp[0] = v.x; dp[1] = v.y; dp[2] = v.z; dp[3] = v.w;
    }
    __syncthreads();
    #pragma unroll 4
    for (int k = 0; k < K; k++) {
        float hv = lrow[k];
        const float* wk = &w_l[(size_t)k * 128 + j0];
        #pragma unroll
        for (int j = 0; j < 32; j++) acc[j] = fmaf(hv, wk[j], acc[j]);
    }

    if (!valid) return;
    float4* o4 = (float4*)out;
    #pragma unroll
    for (int jj = 0; jj < 8; jj++) {
        float4 v;
        v.x = fmaxf(acc[jj * 4 + 0], 0.f);
        v.y = fmaxf(acc[jj * 4 + 1], 0.f);
        v.z = fmaxf(acc[jj * 4 + 2], 0.f);
        v.w = fmaxf(acc[jj * 4 + 3], 0.f);
        o4[(size_t)node * 32 + (j0 >> 2) + jj] = v;
    }
}

// ---------------------------------------------------------------- pool + head
// batch sorted; one block per graph; binary-search segment; fused head GEMV
__global__ void k_pool_head(const float* __restrict__ h2, const int* __restrict__ batch,
                            const float* __restrict__ w_out, const float* __restrict__ b_out,
                            float* __restrict__ out) {
    int g = blockIdx.x;
    int lo = 0, hi = N_NODES;
    while (lo < hi) { int mid = (lo + hi) >> 1; if (batch[mid] < g) lo = mid + 1; else hi = mid; }
    int s = lo;
    lo = s; hi = N_NODES;
    while (lo < hi) { int mid = (lo + hi) >> 1; if (batch[mid] < g + 1) lo = mid + 1; else hi = mid; }
    int e = lo;

    int f = threadIdx.x & 127, half = threadIdx.x >> 7;
    float acc = 0.0f;
    for (int r = s + half; r < e; r += 2) acc += h2[(size_t)r * 128 + f];
    __shared__ float tmp[256];
    tmp[threadIdx.x] = acc;
    __syncthreads();
    if (half == 0) {
        float p = (tmp[f] + tmp[f + 128]) / (float)max(e - s, 1);
        tmp[f]       = p * w_out[f * 2 + 0];
        tmp[f + 128] = p * w_out[f * 2 + 1];
    }
    __syncthreads();
    for (int str = 64; str > 0; str >>= 1) {
        if (threadIdx.x < str) {
            tmp[threadIdx.x] += tmp[threadIdx.x + str];
            tmp[threadIdx.x + 128] += tmp[threadIdx.x + 128 + str];
        }
        __syncthreads();
    }
    if (threadIdx.x == 0) {
        out[(size_t)g * 2 + 0] = tmp[0] + b_out[0];
        out[(size_t)g * 2 + 1] = tmp[128] + b_out[1];
    }
}

// ---------------------------------------------------------------- launch
extern "C" void kernel_launch(void* const* d_in, const int* in_sizes, int n_in,
                              void* d_out, int out_size, void* d_ws, size_t ws_size,
                              hipStream_t stream) {
    const int*   x      = (const int*)d_in[0];
    const int*   ei     = (const int*)d_in[1];
    const int*   batch  = (const int*)d_in[2];
    const float* emb    = (const float*)d_in[3];
    const float* w1_l   = (const float*)d_in[4];
    const float* b1     = (const float*)d_in[5];
    const float* w1_r   = (const float*)d_in[6];
    const float* w2_l   = (const float*)d_in[7];
    const float* b2     = (const float*)d_in[8];
    const float* w2_r   = (const float*)d_in[9];
    const float* w_out  = (const float*)d_in[10];
    const float* b_out  = (const float*)d_in[11];
    float* out = (float*)d_out;

    // workspace layout (floats)
    float* F = (float*)d_ws;
    float* h0    = F;                                 // N*64
    float* mean1 = h0 + (size_t)N_NODES * 64;         // N*64
    float* h1    = mean1 + (size_t)N_NODES * 64;      // N*128
    float* mean2 = h1 + (size_t)N_NODES * 128;        // N*128
    float* h2    = h0;                                // alias: N*128 (h0+mean1 dead)
    int*   deg   = (int*)(mean2 + (size_t)N_NODES * 128);
    int*   rowptr= deg + N_NODES;                     // N+1
    int*   wp    = rowptr + N_NODES + 1;              // N
    int*   nbr   = wp + N_NODES;                      // E
    int*   bsums = nbr + N_EDGES;                     // 256

    const int NB = (N_NODES + 255) / 256;             // 196

    hipMemsetAsync(deg, 0, (size_t)N_NODES * sizeof(int), stream);

    k_embed_hist<<<(N_EDGES + 255) / 256, 256, 0, stream>>>(x, emb, ei, h0, deg);
    k_scanA<<<NB, 256, 0, stream>>>(deg, rowptr, bsums);
    k_scanB<<<1, 256, 0, stream>>>(bsums, NB);
    k_scanC<<<NB, 256, 0, stream>>>(rowptr, wp, bsums);
    k_scatter<<<(N_EDGES + 255) / 256, 256, 0, stream>>>(ei, wp, nbr);

    // layer 1
    k_agg<64><<<(N_NODES + 3) / 4, 256, 0, stream>>>(h0, rowptr, nbr, mean1);
    k_layer<64><<<(N_NODES + 63) / 64, 256, 0, stream>>>(h0, mean1, w1_r, w1_l, b1, h1);

    // layer 2
    k_agg<128><<<(N_NODES + 3) / 4, 256, 0, stream>>>(h1, rowptr, nbr, mean2);
    k_layer<128><<<(N_NODES + 63) / 64, 256, 0, stream>>>(h1, mean2, w2_r, w2_l, b2, h2);

    // pool + head
    k_pool_head<<<N_GRAPHS, 256, 0, stream>>>(h2, batch, w_out, b_out, out);

    (void)in_sizes; (void)n_in; (void)out_size; (void)ws_size;
}

// Round 4
// 387.255 us; speedup vs baseline: 1.1365x; 1.0011x over previous
//
#include <hip/hip_runtime.h>
#include <hip/hip_bf16.h>

#define N_NODES 50000
#define N_EDGES 800000
#define N_GRAPHS 512
#define EMB 64
#define HID 128

// -------------------------------------------- embed gather + degree histogram
// N_NODES*16 == N_EDGES == 800000: one grid does both.
__global__ void k_embed_hist(const int* __restrict__ x, const float* __restrict__ emb,
                             const int* __restrict__ ei, float* __restrict__ h0,
                             int* __restrict__ deg) {
    int t = blockIdx.x * 256 + threadIdx.x;
    if (t >= N_EDGES) return;
    int n = t >> 4, c4 = t & 15;
    const float4* e4 = (const float4*)emb;
    ((float4*)h0)[(size_t)n * 16 + c4] = e4[(size_t)x[n] * 16 + c4];
    atomicAdd(&deg[ei[N_EDGES + t]], 1);
}

// ---------------------------------------------------------------- 3-phase scan
__global__ void k_scanA(const int* __restrict__ deg, int* __restrict__ rowptr,
                        int* __restrict__ bsums) {
    __shared__ int s[256];
    int t = threadIdx.x, i = blockIdx.x * 256 + t;
    int v = (i < N_NODES) ? deg[i] : 0;
    s[t] = v; __syncthreads();
    int xv = v;
    for (int off = 1; off < 256; off <<= 1) {
        int y = (t >= off) ? s[t - off] : 0;
        __syncthreads();
        xv += y; s[t] = xv;
        __syncthreads();
    }
    if (i < N_NODES) rowptr[i] = xv - v;
    if (t == 255) bsums[blockIdx.x] = xv;
}

__global__ void k_scanB(int* __restrict__ bsums, int nb) {
    __shared__ int s[256];
    int t = threadIdx.x;
    int v = (t < nb) ? bsums[t] : 0;
    s[t] = v; __syncthreads();
    int xv = v;
    for (int off = 1; off < 256; off <<= 1) {
        int y = (t >= off) ? s[t - off] : 0;
        __syncthreads();
        xv += y; s[t] = xv;
        __syncthreads();
    }
    if (t < nb) bsums[t] = xv - v;
}

__global__ void k_scanC(int* __restrict__ rowptr, int* __restrict__ wp,
                        const int* __restrict__ bsums) {
    int i = blockIdx.x * 256 + threadIdx.x;
    if (i < N_NODES) {
        int v = rowptr[i] + bsums[blockIdx.x];
        rowptr[i] = v;
        wp[i] = v;
    }
    if (i == 0) rowptr[N_NODES] = N_EDGES;
}

// ---------------------------------------------------------------- edge scatter
__global__ void k_scatter(const int* __restrict__ ei, int* __restrict__ wp,
                          int* __restrict__ nbr) {
    int e = blockIdx.x * 256 + threadIdx.x;
    if (e >= N_EDGES) return;
    int s = ei[e], d = ei[N_EDGES + e];
    int pos = atomicAdd(&wp[d], 1);
    nbr[pos] = s;
}

// ---------------------------------------------------------------- aggregation
// Multi-node waves: F=128 -> 2 nodes/wave (32 lanes x float4 = 512B row);
// F=64 -> 4 nodes/wave (16 lanes x float4). Unroll-4 independent accumulators.
template <int F>
__global__ __launch_bounds__(256) void k_agg(const float* __restrict__ h,
                                             const int* __restrict__ rowptr,
                                             const int* __restrict__ nbr,
                                             float* __restrict__ mean) {
    int w = (blockIdx.x * 256 + threadIdx.x) >> 6;   // wave id
    int l = threadIdx.x & 63;
    const float4* h4 = (const float4*)h;
    float4* m4 = (float4*)mean;

    int n, c;
    if constexpr (F == 128) { n = w * 2 + (l >> 5); c = l & 31; }
    else                    { n = w * 4 + (l >> 4); c = l & 15; }
    if (n >= N_NODES) return;
    constexpr int C = F / 4;                          // float4 per row

    int r0 = rowptr[n], r1 = rowptr[n + 1];
    float inv = 1.0f / (float)max(r1 - r0, 1);

    float4 a0 = {0,0,0,0}, a1 = {0,0,0,0}, a2 = {0,0,0,0}, a3 = {0,0,0,0};
    int i = r0;
    for (; i + 3 < r1; i += 4) {
        int s0 = nbr[i], s1 = nbr[i + 1], s2 = nbr[i + 2], s3 = nbr[i + 3];
        float4 v0 = h4[(size_t)s0 * C + c];
        float4 v1 = h4[(size_t)s1 * C + c];
        float4 v2 = h4[(size_t)s2 * C + c];
        float4 v3 = h4[(size_t)s3 * C + c];
        a0.x += v0.x; a0.y += v0.y; a0.z += v0.z; a0.w += v0.w;
        a1.x += v1.x; a1.y += v1.y; a1.z += v1.z; a1.w += v1.w;
        a2.x += v2.x; a2.y += v2.y; a2.z += v2.z; a2.w += v2.w;
        a3.x += v3.x; a3.y += v3.y; a3.z += v3.z; a3.w += v3.w;
    }
    for (; i < r1; ++i) {
        float4 v = h4[(size_t)nbr[i] * C + c];
        a0.x += v.x; a0.y += v.y; a0.z += v.z; a0.w += v.w;
    }
    float4 r;
    r.x = ((a0.x + a1.x) + (a2.x + a3.x)) * inv;
    r.y = ((a0.y + a1.y) + (a2.y + a3.y)) * inv;
    r.z = ((a0.z + a1.z) + (a2.z + a3.z)) * inv;
    r.w = ((a0.w + a1.w) + (a2.w + a3.w)) * inv;
    m4[(size_t)n * C + c] = r;
}

// ---------------------------------------------------------------- fused layer
// out = relu(bias + hself@w_r + hmean@w_l). block = 64 nodes x 8 waves (512thr),
// wave w -> out cols [16w,16w+16), lane -> node, acc[16] in regs across both
// passes. Weights via uniform s_loads. LDS stride K+1 (2-way alias = free).
template <int K>
__global__ __launch_bounds__(512) void k_layer(
    const float* __restrict__ hself, const float* __restrict__ hmean,
    const float* __restrict__ w_r, const float* __restrict__ w_l,
    const float* __restrict__ bias, float* __restrict__ out) {
    constexpr int LS = K + 1;
    __shared__ float ls[64 * LS];
    int base = blockIdx.x * 64;
    int t = threadIdx.x;
    int lane = t & 63;
    int wid = __builtin_amdgcn_readfirstlane(t >> 6);  // 0..7
    int j0 = wid * 16;
    int node = base + lane;
    bool valid = node < N_NODES;

    float acc[16];
    #pragma unroll
    for (int j = 0; j < 16; j++) acc[j] = bias[j0 + j];

    const float* lrow = &ls[lane * LS];

    // ---- pass 1: hself @ w_r
    {
        const float4* h4 = (const float4*)hself;
        for (int idx = t; idx < 64 * (K / 4); idx += 512) {
            int r = idx / (K / 4), c4 = idx % (K / 4);
            float4 v = (base + r < N_NODES) ? h4[(size_t)(base + r) * (K / 4) + c4]
                                            : make_float4(0.f, 0.f, 0.f, 0.f);
            float* dp = &ls[r * LS + c4 * 4];
            dp[0] = v.x; dp[1] = v.y; dp[2] = v.z; dp[3] = v.w;
        }
    }
    __syncthreads();
    #pragma unroll 4
    for (int k = 0; k < K; k++) {
        float hv = lrow[k];
        const float* wk = &w_r[(size_t)k * 128 + j0];
        #pragma unroll
        for (int j = 0; j < 16; j++) acc[j] = fmaf(hv, wk[j], acc[j]);
    }
    __syncthreads();   // all waves done reading pass-1 tile

    // ---- pass 2: hmean @ w_l
    {
        const float4* h4 = (const float4*)hmean;
        for (int idx = t; idx < 64 * (K / 4); idx += 512) {
            int r = idx / (K / 4), c4 = idx % (K / 4);
            float4 v = (base + r < N_NODES) ? h4[(size_t)(base + r) * (K / 4) + c4]
                                            : make_float4(0.f, 0.f, 0.f, 0.f);
            float* dp = &ls[r * LS + c4 * 4];
            dp[0] = v.x; dp[1] = v.y; dp[2] = v.z; dp[3] = v.w;
        }
    }
    __syncthreads();
    #pragma unroll 4
    for (int k = 0; k < K; k++) {
        float hv = lrow[k];
        const float* wk = &w_l[(size_t)k * 128 + j0];
        #pragma unroll
        for (int j = 0; j < 16; j++) acc[j] = fmaf(hv, wk[j], acc[j]);
    }

    if (!valid) return;
    float4* o4 = (float4*)out;
    #pragma unroll
    for (int jj = 0; jj < 4; jj++) {
        float4 v;
        v.x = fmaxf(acc[jj * 4 + 0], 0.f);
        v.y = fmaxf(acc[jj * 4 + 1], 0.f);
        v.z = fmaxf(acc[jj * 4 + 2], 0.f);
        v.w = fmaxf(acc[jj * 4 + 3], 0.f);
        o4[(size_t)node * 32 + wid * 4 + jj] = v;
    }
}

// ---------------------------------------------------------------- pool + head
__global__ void k_pool_head(const float* __restrict__ h2, const int* __restrict__ batch,
                            const float* __restrict__ w_out, const float* __restrict__ b_out,
                            float* __restrict__ out) {
    int g = blockIdx.x;
    int lo = 0, hi = N_NODES;
    while (lo < hi) { int mid = (lo + hi) >> 1; if (batch[mid] < g) lo = mid + 1; else hi = mid; }
    int s = lo;
    lo = s; hi = N_NODES;
    while (lo < hi) { int mid = (lo + hi) >> 1; if (batch[mid] < g + 1) lo = mid + 1; else hi = mid; }
    int e = lo;

    int f = threadIdx.x & 127, half = threadIdx.x >> 7;
    float acc = 0.0f;
    for (int r = s + half; r < e; r += 2) acc += h2[(size_t)r * 128 + f];
    __shared__ float tmp[256];
    tmp[threadIdx.x] = acc;
    __syncthreads();
    if (half == 0) {
        float p = (tmp[f] + tmp[f + 128]) / (float)max(e - s, 1);
        tmp[f]       = p * w_out[f * 2 + 0];
        tmp[f + 128] = p * w_out[f * 2 + 1];
    }
    __syncthreads();
    for (int str = 64; str > 0; str >>= 1) {
        if (threadIdx.x < str) {
            tmp[threadIdx.x] += tmp[threadIdx.x + str];
            tmp[threadIdx.x + 128] += tmp[threadIdx.x + 128 + str];
        }
        __syncthreads();
    }
    if (threadIdx.x == 0) {
        out[(size_t)g * 2 + 0] = tmp[0] + b_out[0];
        out[(size_t)g * 2 + 1] = tmp[128] + b_out[1];
    }
}

// ---------------------------------------------------------------- launch
extern "C" void kernel_launch(void* const* d_in, const int* in_sizes, int n_in,
                              void* d_out, int out_size, void* d_ws, size_t ws_size,
                              hipStream_t stream) {
    const int*   x      = (const int*)d_in[0];
    const int*   ei     = (const int*)d_in[1];
    const int*   batch  = (const int*)d_in[2];
    const float* emb    = (const float*)d_in[3];
    const float* w1_l   = (const float*)d_in[4];
    const float* b1     = (const float*)d_in[5];
    const float* w1_r   = (const float*)d_in[6];
    const float* w2_l   = (const float*)d_in[7];
    const float* b2     = (const float*)d_in[8];
    const float* w2_r   = (const float*)d_in[9];
    const float* w_out  = (const float*)d_in[10];
    const float* b_out  = (const float*)d_in[11];
    float* out = (float*)d_out;

    // workspace layout (floats)
    float* F = (float*)d_ws;
    float* h0    = F;                                 // N*64
    float* mean1 = h0 + (size_t)N_NODES * 64;         // N*64
    float* h1    = mean1 + (size_t)N_NODES * 64;      // N*128
    float* mean2 = h1 + (size_t)N_NODES * 128;        // N*128
    float* h2    = h0;                                // alias: N*128 (h0+mean1 dead)
    int*   deg   = (int*)(mean2 + (size_t)N_NODES * 128);
    int*   rowptr= deg + N_NODES;                     // N+1
    int*   wp    = rowptr + N_NODES + 1;              // N
    int*   nbr   = wp + N_NODES;                      // E
    int*   bsums = nbr + N_EDGES;                     // 256

    const int NB = (N_NODES + 255) / 256;             // 196

    hipMemsetAsync(deg, 0, (size_t)N_NODES * sizeof(int), stream);

    k_embed_hist<<<(N_EDGES + 255) / 256, 256, 0, stream>>>(x, emb, ei, h0, deg);
    k_scanA<<<NB, 256, 0, stream>>>(deg, rowptr, bsums);
    k_scanB<<<1, 256, 0, stream>>>(bsums, NB);
    k_scanC<<<NB, 256, 0, stream>>>(rowptr, wp, bsums);
    k_scatter<<<(N_EDGES + 255) / 256, 256, 0, stream>>>(ei, wp, nbr);

    // layer 1: agg waves = N/4 -> blocks = N/16
    k_agg<64><<<(N_NODES + 15) / 16, 256, 0, stream>>>(h0, rowptr, nbr, mean1);
    k_layer<64><<<(N_NODES + 63) / 64, 512, 0, stream>>>(h0, mean1, w1_r, w1_l, b1, h1);

    // layer 2: agg waves = N/2 -> blocks = N/8
    k_agg<128><<<(N_NODES + 7) / 8, 256, 0, stream>>>(h1, rowptr, nbr, mean2);
    k_layer<128><<<(N_NODES + 63) / 64, 512, 0, stream>>>(h1, mean2, w2_r, w2_l, b2, h2);

    // pool + head
    k_pool_head<<<N_GRAPHS, 256, 0, stream>>>(h2, batch, w_out, b_out, out);

    (void)in_sizes; (void)n_in; (void)out_size; (void)ws_size;
}